// Round 1
// 139.307 us; speedup vs baseline: 1.0653x; 1.0653x over previous
//
#include <hip/hip_runtime.h>

// Problem constants (fixed by the reference)
#define BATCH   128
#define C_IN    3
#define C_OUT   16
#define F4_PER_PLANE 16384             // 256*256/4 float4 per plane
#define THREADS 1024                   // 16 waves
#define NWAVES  (THREADS / 64)
#define NBLK    (BATCH * 2)            // 2 blocks per batch -> 256 blocks, 1/CU
#define F4_STREAM (3 * F4_PER_PLANE / 2)  // 24576 float4 = 384 KB contiguous per block
#define ITERS   (F4_STREAM / THREADS)     // 24

// Clang ext-vector so __builtin_nontemporal_load works on the 16B load.
typedef float f32x4 __attribute__((ext_vector_type(4)));

// Main kernel: 256 blocks (one per CU), each reduces ONE CONTIGUOUS 384 KB
// stream (half of its batch's 3 planes laid out back-to-back) instead of the
// previous 3 interleaved plane-strided streams. Plane boundaries fall exactly
// on iteration boundaries (16384 % 1024 == 0), so per-plane routing is
// compile-time static. Nontemporal loads: data is touched exactly once, skip
// L2/L3 allocation. No atomics, no fences (cross-block sync >=8 us measured
// in prior session); visibility via the kernel boundary before the tail.
__global__ __launch_bounds__(THREADS) void main_reduce(
        const float* __restrict__ x,        // (B, 3, 256, 256)
        float* __restrict__ part) {         // 256 slots x 4 floats
    const int b    = blockIdx.x >> 1;
    const int half = blockIdx.x & 1;
    const int t    = threadIdx.x;
    const f32x4* xp = (const f32x4*)x
                    + (size_t)b * (3 * F4_PER_PLANE) + (size_t)half * F4_STREAM;

    float a0 = 0.0f, a1 = 0.0f, a2 = 0.0f;
    if (half == 0) {
        // iters 0..15 -> plane 0 (full), 16..23 -> plane 1 (first half)
#pragma unroll
        for (int i = 0; i < 16; ++i) {
            f32x4 v = __builtin_nontemporal_load(&xp[i * THREADS + t]);
            a0 += (v.x + v.y) + (v.z + v.w);
        }
#pragma unroll
        for (int i = 16; i < 24; ++i) {
            f32x4 v = __builtin_nontemporal_load(&xp[i * THREADS + t]);
            a1 += (v.x + v.y) + (v.z + v.w);
        }
    } else {
        // iters 0..7 -> plane 1 (second half), 8..23 -> plane 2 (full)
#pragma unroll
        for (int i = 0; i < 8; ++i) {
            f32x4 v = __builtin_nontemporal_load(&xp[i * THREADS + t]);
            a1 += (v.x + v.y) + (v.z + v.w);
        }
#pragma unroll
        for (int i = 8; i < 24; ++i) {
            f32x4 v = __builtin_nontemporal_load(&xp[i * THREADS + t]);
            a2 += (v.x + v.y) + (v.z + v.w);
        }
    }

#pragma unroll
    for (int off = 32; off > 0; off >>= 1) {
        a0 += __shfl_down(a0, off, 64);
        a1 += __shfl_down(a1, off, 64);
        a2 += __shfl_down(a2, off, 64);
    }
    __shared__ float smem[NWAVES][3];
    const int lane = t & 63;
    const int wv   = t >> 6;
    if (lane == 0) { smem[wv][0] = a0; smem[wv][1] = a1; smem[wv][2] = a2; }
    __syncthreads();

    if (t == 0) {
        float S0 = 0.0f, S1 = 0.0f, S2 = 0.0f;
#pragma unroll
        for (int w = 0; w < NWAVES; ++w) {
            S0 += smem[w][0]; S1 += smem[w][1]; S2 += smem[w][2];
        }
        float* slot = part + blockIdx.x * 4;
        slot[0] = S0; slot[1] = S1; slot[2] = S2;
    }
}

// Tail kernel: one block, one thread per batch. Combine the 2 half-partials
// (half0 gives plane0 + first-half plane1; half1 gives rest), fold the 3x16
// kernel sums + bias + logsumexp, x10.
__global__ __launch_bounds__(BATCH) void finalize(
        const float* __restrict__ part,
        const float* __restrict__ weight,   // (C_IN, C_OUT, 3, 3) flat
        const float* __restrict__ bias,     // (C_OUT,)
        float* __restrict__ out) {          // (BATCH,)
    __shared__ float Wsum[C_IN][C_OUT];
    __shared__ float bsh[C_OUT];
    const int t = threadIdx.x;
    if (t < C_IN * C_OUT) {
        float s = 0.0f;
#pragma unroll
        for (int k = 0; k < 9; ++k) s += weight[t * 9 + k];
        Wsum[t / C_OUT][t % C_OUT] = s;
    }
    if (t < C_OUT) bsh[t] = bias[t];
    __syncthreads();

    const float* s0 = part + (t * 2 + 0) * 4;
    const float* s1 = part + (t * 2 + 1) * 4;
    const float S[C_IN] = { s0[0] + s1[0], s0[1] + s1[1], s0[2] + s1[2] };

    const float inv_area = 1.0f / (258.0f * 258.0f);
    float m[C_OUT];
    float mmax = -1e30f;
#pragma unroll
    for (int co = 0; co < C_OUT; ++co) {
        float v = (S[0] * Wsum[0][co] + S[1] * Wsum[1][co] + S[2] * Wsum[2][co])
                      * inv_area + bsh[co];
        m[co] = v;
        mmax = fmaxf(mmax, v);
    }
    float se = 0.0f;
#pragma unroll
    for (int co = 0; co < C_OUT; ++co) se += expf(m[co] - mmax);
    out[t] = 10.0f * (logf(se) + mmax);
}

extern "C" void kernel_launch(void* const* d_in, const int* in_sizes, int n_in,
                              void* d_out, int out_size, void* d_ws, size_t ws_size,
                              hipStream_t stream) {
    const float* x      = (const float*)d_in[0];
    const float* weight = (const float*)d_in[1];
    const float* bias   = (const float*)d_in[2];
    float* out  = (float*)d_out;
    float* part = (float*)d_ws;   // 256 slots x 4 floats = 4 KB

    main_reduce<<<NBLK, THREADS, 0, stream>>>(x, part);
    finalize<<<1, BATCH, 0, stream>>>(part, weight, bias, out);
}